// Round 9
// baseline (735.055 us; speedup 1.0000x reference)
//
#include <hip/hip_runtime.h>
#include <math.h>

#define NN 100000
#define DD 128
#define OUT_DIM 256
#define HOPS 3
#define EDGES 640000
#define TGT (HOPS*NN)          // 300000

typedef short bf16x8 __attribute__((ext_vector_type(8)));
typedef float f32x4 __attribute__((ext_vector_type(4)));

__device__ __forceinline__ unsigned short f2bf(float f) {
    unsigned u = __float_as_uint(f);
    unsigned r = u + 0x7FFFu + ((u >> 16) & 1u);   // RNE
    return (unsigned short)(r >> 16);
}
__device__ __forceinline__ float bf2f(unsigned short s) {
    return __uint_as_float(((unsigned)s) << 16);
}
__device__ __forceinline__ float silu(float v) { return v / (1.0f + expf(-v)); }

// XOR-swizzle on element index within 64-elem (128B) chunks keyed by row&7.
// Involution; baked into global bf16 activation buffers (feats/h0/h1) so
// global_load_lds staging stays linear and per-lane 16B fragment loads work.
__device__ __forceinline__ int swz(int c, int r) {
    return (c & ~63) | ((c & 63) ^ ((r & 7) << 3));
}

__device__ __forceinline__ void gload16(const unsigned short* g, unsigned short* l) {
    __builtin_amdgcn_global_load_lds(
        (const __attribute__((address_space(1))) void*)g,
        (__attribute__((address_space(3))) void*)l, 16, 0, 0);
}

// ---------------------------------------------------------------------------
// CSR build: histogram -> block scan -> partial scan -> add-back -> fill
// ---------------------------------------------------------------------------
__global__ __launch_bounds__(256) void k_hist(const int* __restrict__ tgt,
                                              int* __restrict__ cnt) {
    int e = blockIdx.x * 256 + threadIdx.x;
    atomicAdd(&cnt[tgt[e]], 1);
}

__global__ __launch_bounds__(512) void k_scanb(const int* __restrict__ cnt,
                                               int* __restrict__ off,
                                               int* __restrict__ part, int n) {
    __shared__ int s[512];
    int tid = threadIdx.x;
    int g = blockIdx.x * 512 + tid;
    int v = (g < n) ? cnt[g] : 0;
    s[tid] = v;
    __syncthreads();
    for (int d = 1; d < 512; d <<= 1) {
        int a = (tid >= d) ? s[tid - d] : 0;
        __syncthreads();
        s[tid] += a;
        __syncthreads();
    }
    if (g < n) off[g] = s[tid] - v;                  // exclusive
    if (tid == 511) part[blockIdx.x] = s[511];
}

__global__ __launch_bounds__(1024) void k_scanp(int* __restrict__ part, int n) {
    __shared__ int s[1024];
    int t = threadIdx.x;
    s[t] = (t < n) ? part[t] : 0;
    __syncthreads();
    for (int d = 1; d < 1024; d <<= 1) {
        int a = (t >= d) ? s[t - d] : 0;
        __syncthreads();
        s[t] += a;
        __syncthreads();
    }
    if (t < n) part[t] = s[t];                       // inclusive
}

__global__ __launch_bounds__(512) void k_addoff(int* __restrict__ off,
                                                const int* __restrict__ part,
                                                int* __restrict__ cursor, int n) {
    int g = blockIdx.x * 512 + threadIdx.x;
    if (g >= n) return;
    int add = (blockIdx.x > 0) ? part[blockIdx.x - 1] : 0;
    int o = off[g] + add;
    off[g] = o;
    cursor[g] = o;
}

__global__ __launch_bounds__(256) void k_fill(const int* __restrict__ tgt,
                                              const int* __restrict__ src,
                                              int* __restrict__ cursor,
                                              int* __restrict__ esrc) {
    int e = blockIdx.x * 256 + threadIdx.x;
    int t = tgt[e];
    int p = atomicAdd(&cursor[t], 1);
    esrc[p] = src[e] % NN;
}

// ---------------------------------------------------------------------------
// Gather-aggregate + feats build (bf16, PRE-SWIZZLED layout).
// ---------------------------------------------------------------------------
__global__ __launch_bounds__(256) void k_aggfeats(const float* __restrict__ x,
                                                  const int* __restrict__ off,
                                                  const int* __restrict__ cur,
                                                  const int* __restrict__ esrc,
                                                  unsigned* __restrict__ feats) {
    int lane = threadIdx.x & 63;
    int r = blockIdx.x * 4 + (threadIdx.x >> 6);
    const float2* x2 = (const float2*)x;
    if (r < NN) {
        float2 v = x2[(size_t)r * 64 + lane];
        int p = lane;                                // pairs 0..63
        int ps = (p & ~31) | ((p & 31) ^ ((r & 7) << 2));
        feats[(size_t)r * 256 + ps] =
            (unsigned)f2bf(v.x) | ((unsigned)f2bf(v.y) << 16);
    } else {
        int t = r - NN;
        int hop = t / NN;
        int tn = t - hop * NN;
        int b = off[t], e = cur[t];
        float ax = 0.f, ay = 0.f;
        for (int i = b; i < e; ++i) {
            int sn = esrc[i];
            float2 v = x2[(size_t)sn * 64 + lane];
            ax += v.x; ay += v.y;
        }
        int p = 64 + hop * 64 + lane;                // pairs 64..255
        int ps = (p & ~31) | ((p & 31) ^ ((tn & 7) << 2));
        feats[(size_t)tn * 256 + ps] =
            (unsigned)f2bf(ax) | ((unsigned)f2bf(ay) << 16);
    }
}

// ---------------------------------------------------------------------------
// Weight prep.
// Wt1: [c][k] pre-swizzled in k (gload_lds-staged by gemm1, XOR read).
// Wt25: TILED layout per matrix: [tile(8)][o(4)][col(256)][8], where
//       logical k = tile*32 + o*8 + e. Staging reads are then fully linear
//       and the LDS image [o][col][8] is bank-conflict-free for B-frags.
// ---------------------------------------------------------------------------
__global__ __launch_bounds__(256) void k_wprep(
    const float* __restrict__ Win, const float* __restrict__ Wskip,
    const float* __restrict__ W10, const float* __restrict__ W20,
    const float* __restrict__ W11, const float* __restrict__ W21,
    unsigned short* __restrict__ Wt1, unsigned short* __restrict__ Wt25) {
    int idx = blockIdx.x * 256 + threadIdx.x;        // grid = 2048 blocks
    if (idx < 262144) {
        int c = idx >> 9, k = idx & 511;
        int kl = swz(k, c);                          // logical k stored at slot k
        float v = (c < 256) ? Win[kl * 256 + c] : Wskip[kl * 256 + (c - 256)];
        Wt1[idx] = f2bf(v);
    } else {
        int j = idx - 262144;
        int m = j >> 16, r = j & 65535;
        int tk = r >> 13;                            // 0..7
        int o  = (r >> 11) & 3;                      // 0..3
        int col = (r >> 3) & 255;
        int e  = r & 7;
        int k  = tk * 32 + o * 8 + e;                // logical k
        const float* Wm = (m == 0) ? W10 : (m == 1) ? W20 : (m == 2) ? W11 : W21;
        Wt25[(size_t)m * 65536 + r] = f2bf(Wm[k * 256 + col]);
    }
}

// ---------------------------------------------------------------------------
// GEMM1: feats[N,512]swz @ Wt1[512c][512k]swz. BM=BN=128, BK=64, 4 waves.
// A-frags DIRECT from global (reg-dbuf, one step ahead); B staged via
// gload_lds dbuf (32 KB LDS total -> 3 blocks/CU). Counted vmcnt(8) keeps
// the 8 A-prefetch loads in flight across the barrier.
// cols 0-255 -> h0 = bf16 silu (swz); 256-511 -> gsk bf16 linear.
// ---------------------------------------------------------------------------
__global__ __launch_bounds__(256, 3) void k_gemm1(
    const unsigned short* __restrict__ A, const unsigned short* __restrict__ Wt,
    const float* __restrict__ bias0, const float* __restrict__ bias1,
    unsigned short* __restrict__ h0, unsigned short* __restrict__ gsk) {
    const int K = 512;
    __shared__ unsigned short Bs[2][128 * 64];       // 32 KB

    const int tid = threadIdx.x;
    const int lane = tid & 63;
    const int w = tid >> 6;
    const int row0 = blockIdx.x * 128;
    const int col0 = blockIdx.y * 128;

    const int wr = (w >> 1) * 64;
    const int wc = (w & 1) * 64;
    const int lr = lane & 15;
    const int lk8 = (lane >> 4) * 8;

    f32x4 acc[4][4];
    #pragma unroll
    for (int m = 0; m < 4; ++m)
        #pragma unroll
        for (int n = 0; n < 4; ++n) acc[m][n] = (f32x4){0.f, 0.f, 0.f, 0.f};

    auto STAGE_B = [&](int buf, int k0) {
        #pragma unroll
        for (int i = 0; i < 4; ++i) {
            int chunk = i * 4 + w;                   // wave-uniform
            int slot = chunk * 64 + lane;
            int r = slot >> 3;                       // 0..127
            int kq = (slot & 7) * 8;                 // 0..56
            gload16(Wt + (size_t)(col0 + r) * K + k0 + kq, &Bs[buf][chunk * 512]);
        }
    };

    bf16x8 a[2][4][2];
    auto LOAD_A = [&](int buf, int ks) {
        #pragma unroll
        for (int m = 0; m < 4; ++m) {
            int row = row0 + wr + m * 16 + lr;
            #pragma unroll
            for (int k2 = 0; k2 < 2; ++k2) {
                int k = ks * 64 + k2 * 32 + lk8;
                int eo = (k & ~63) | ((k & 63) ^ ((row & 7) << 3));
                a[buf][m][k2] = *(const bf16x8*)(A + (size_t)row * K + eo);
            }
        }
    };

    LOAD_A(0, 0);
    STAGE_B(0, 0);
    asm volatile("s_waitcnt vmcnt(0)" ::: "memory");
    __syncthreads();

    #pragma unroll
    for (int ks = 0; ks < 8; ++ks) {
        int cur = ks & 1;
        if (ks < 7) {
            STAGE_B(cur ^ 1, (ks + 1) * 64);         // 4 gload_lds
            LOAD_A(cur ^ 1, ks + 1);                 // 8 global->reg, in flight
        }
        #pragma unroll
        for (int k2 = 0; k2 < 2; ++k2) {
            bf16x8 bfr[4];
            #pragma unroll
            for (int n = 0; n < 4; ++n) {
                int row = wc + n * 16 + lr;
                int eo = (k2 * 32 + lk8) ^ ((row & 7) << 3);
                bfr[n] = *(const bf16x8*)&Bs[cur][row * 64 + eo];
            }
            #pragma unroll
            for (int m = 0; m < 4; ++m)
                #pragma unroll
                for (int n = 0; n < 4; ++n)
                    acc[m][n] = __builtin_amdgcn_mfma_f32_16x16x32_bf16(
                        a[cur][m][k2], bfr[n], acc[m][n], 0, 0, 0);
        }
        if (ks < 7) {
            asm volatile("s_waitcnt vmcnt(8)" ::: "memory");  // B-stage done, A stays in flight
        }
        __syncthreads();
    }

    const int rq = (lane >> 4) * 4;
    #pragma unroll
    for (int m = 0; m < 4; ++m) {
        #pragma unroll
        for (int n = 0; n < 4; ++n) {
            int cg = col0 + wc + n * 16 + lr;        // 0..511
            float bb = (cg < OUT_DIM) ? bias0[cg] : bias1[cg - OUT_DIM];
            #pragma unroll
            for (int j = 0; j < 4; ++j) {
                int r = row0 + wr + m * 16 + rq + j;
                if (r >= NN) continue;
                float v = acc[m][n][j] + bb;
                if (cg < OUT_DIM)
                    h0[(size_t)r * OUT_DIM + swz(cg, r)] = f2bf(silu(v));
                else
                    gsk[(size_t)r * OUT_DIM + (cg - OUT_DIM)] = f2bf(v);
            }
        }
    }
}

// ---------------------------------------------------------------------------
// Fused residual MLP block v2: Hout = silu(Hin@W1+b1)@W2 + b2 + Hin [+ gsk]
// 8 waves, BM=128, wave-tile 32x128. LDS = Hs 64 KB + Ws 16 KB = 80 KB
// -> 2 blocks/CU (4 waves/SIMD). W tiles (k32) stream global->reg->LDS
// (T14: loads issued one full compute phase early). Residual folded from
// global at epilogue so acc is reused for both GEMMs (VGPR <= 128).
// ---------------------------------------------------------------------------
template <int FINAL>
__global__ __launch_bounds__(512, 4) void k_mlp(
    const unsigned short* __restrict__ Hin,
    const unsigned short* __restrict__ W1t, const unsigned short* __restrict__ W2t,
    const float* __restrict__ b1, const float* __restrict__ b2,
    const unsigned short* __restrict__ gsk,
    unsigned short* __restrict__ Hout, float* __restrict__ outf) {
    __shared__ unsigned short Hs[128 * 256];         // 64 KB: Hin, then t
    __shared__ unsigned short Ws[8192];              // 16 KB: one k32 W-tile [o][col][8]

    const int tid = threadIdx.x;
    const int lane = tid & 63;
    const int w = tid >> 6;                          // 0..7
    const int wr = (w >> 1) * 32;
    const int wc = (w & 1) * 128;
    const int lr = lane & 15;
    const int lk8 = (lane >> 4) * 8;
    const int o16 = (lane >> 4) * 256;               // Ws o-block (16B units)
    const int row0 = blockIdx.x * 128;

    bf16x8 wA, wB;
    auto LOADW = [&](int t) {                        // t in 0..15
        const unsigned short* base = ((t < 8) ? W1t : W2t) + (t & 7) * 8192;
        wA = *(const bf16x8*)(base + tid * 16);
        wB = *(const bf16x8*)(base + tid * 16 + 8);
    };
    auto PUTW = [&]() {
        *(bf16x8*)&Ws[tid * 16] = wA;
        *(bf16x8*)&Ws[tid * 16 + 8] = wB;
    };

    // prologue: stage Hin panel (gload_lds, linear copy of pre-swizzled rows)
    #pragma unroll
    for (int i = 0; i < 8; ++i) {
        int chunk = w * 8 + i;                       // 0..63, wave-uniform
        gload16(Hin + (size_t)row0 * 256 + chunk * 512 + lane * 8, &Hs[chunk * 512]);
    }
    LOADW(0);
    asm volatile("s_waitcnt vmcnt(0)" ::: "memory");
    __syncthreads();
    PUTW();
    LOADW(1);
    __syncthreads();

    f32x4 acc[2][8];
    #pragma unroll
    for (int m = 0; m < 2; ++m)
        #pragma unroll
        for (int n = 0; n < 8; ++n) acc[m][n] = (f32x4){0.f, 0.f, 0.f, 0.f};

    // ---- GEMM A: acc = Hin @ W1   (8 tiles of k=32)
    #pragma unroll
    for (int s = 0; s < 8; ++s) {
        bf16x8 af[2], bfr[8];
        int kk = s * 32 + lk8;
        #pragma unroll
        for (int m = 0; m < 2; ++m) {
            int row = wr + m * 16 + lr;
            int eo = (kk & ~63) | ((kk & 63) ^ ((row & 7) << 3));
            af[m] = *(const bf16x8*)&Hs[row * 256 + eo];
        }
        #pragma unroll
        for (int n = 0; n < 8; ++n)
            bfr[n] = *(const bf16x8*)&Ws[(o16 + wc + n * 16 + lr) * 8];
        #pragma unroll
        for (int m = 0; m < 2; ++m)
            #pragma unroll
            for (int n = 0; n < 8; ++n)
                acc[m][n] = __builtin_amdgcn_mfma_f32_16x16x32_bf16(
                    af[m], bfr[n], acc[m][n], 0, 0, 0);
        __syncthreads();                             // Ws consumed by all waves
        PUTW();                                      // tile s+1 (reg dep waits)
        LOADW(s + 2);                                // tiles 2..9, in flight
        __syncthreads();                             // Ws (tile s+1) visible
    }

    // ---- transition: t = bf16(silu(acc + b1)) overwrites Hs; acc = b2
    const int rq = (lane >> 4) * 4;
    #pragma unroll
    for (int m = 0; m < 2; ++m)
        #pragma unroll
        for (int n = 0; n < 8; ++n) {
            int col = wc + n * 16 + lr;
            float bb = b1[col];
            #pragma unroll
            for (int j = 0; j < 4; ++j) {
                int row = wr + m * 16 + rq + j;
                Hs[row * 256 + swz(col, row)] = f2bf(silu(acc[m][n][j] + bb));
            }
        }
    __syncthreads();                                 // t visible to all waves
    #pragma unroll
    for (int m = 0; m < 2; ++m)
        #pragma unroll
        for (int n = 0; n < 8; ++n) {
            float bb = b2[wc + n * 16 + lr];
            acc[m][n] = (f32x4){bb, bb, bb, bb};
        }

    // ---- GEMM B: acc += t @ W2   (Ws currently = W2 tile 0; wreg = W2 tile 1)
    #pragma unroll
    for (int s = 0; s < 8; ++s) {
        bf16x8 af[2], bfr[8];
        int kk = s * 32 + lk8;
        #pragma unroll
        for (int m = 0; m < 2; ++m) {
            int row = wr + m * 16 + lr;
            int eo = (kk & ~63) | ((kk & 63) ^ ((row & 7) << 3));
            af[m] = *(const bf16x8*)&Hs[row * 256 + eo];
        }
        #pragma unroll
        for (int n = 0; n < 8; ++n)
            bfr[n] = *(const bf16x8*)&Ws[(o16 + wc + n * 16 + lr) * 8];
        #pragma unroll
        for (int m = 0; m < 2; ++m)
            #pragma unroll
            for (int n = 0; n < 8; ++n)
                acc[m][n] = __builtin_amdgcn_mfma_f32_16x16x32_bf16(
                    af[m], bfr[n], acc[m][n], 0, 0, 0);
        if (s < 7) {
            __syncthreads();
            PUTW();                                  // tile s+9
            if (s < 6) LOADW(s + 10);                // tiles 10..15
            __syncthreads();
        }
    }

    // ---- epilogue: + residual (global, pre-swizzled) [+ gsk], write
    #pragma unroll
    for (int m = 0; m < 2; ++m)
        #pragma unroll
        for (int n = 0; n < 8; ++n) {
            int col = wc + n * 16 + lr;
            #pragma unroll
            for (int j = 0; j < 4; ++j) {
                int row = wr + m * 16 + rq + j;
                int r = row0 + row;
                if (r >= NN) continue;
                float v = acc[m][n][j] + bf2f(Hin[(size_t)r * 256 + swz(col, row)]);
                if (FINAL == 0) {
                    Hout[(size_t)r * 256 + swz(col, row)] = f2bf(v);
                } else {
                    size_t ol = (size_t)r * 256 + col;
                    outf[ol] = v + bf2f(gsk[ol]);
                }
            }
        }
}

extern "C" void kernel_launch(void* const* d_in, const int* in_sizes, int n_in,
                              void* d_out, int out_size, void* d_ws, size_t ws_size,
                              hipStream_t stream) {
    const float* x      = (const float*)d_in[0];
    const int*   target = (const int*)d_in[1];
    const int*   src    = (const int*)d_in[2];
    const float* W_in   = (const float*)d_in[3];
    const float* b_in   = (const float*)d_in[4];
    const float* W1_0   = (const float*)d_in[5];
    const float* b1_0   = (const float*)d_in[6];
    const float* W2_0   = (const float*)d_in[7];
    const float* b2_0   = (const float*)d_in[8];
    const float* W1_1   = (const float*)d_in[9];
    const float* b1_1   = (const float*)d_in[10];
    const float* W2_1   = (const float*)d_in[11];
    const float* b2_1   = (const float*)d_in[12];
    const float* W_skip = (const float*)d_in[13];
    const float* b_skip = (const float*)d_in[14];
    float* out = (float*)d_out;

    // workspace layout
    char* p = (char*)d_ws;
    unsigned short* feats = (unsigned short*)p; p += (size_t)NN * 512 * 2;   // 102.4 MB
    unsigned short* h0    = (unsigned short*)p; p += (size_t)NN * 256 * 2;   // 51.2 MB
    unsigned short* h1    = (unsigned short*)p; p += (size_t)NN * 256 * 2;
    unsigned short* gsk   = (unsigned short*)p; p += (size_t)NN * 256 * 2;
    unsigned short* Wt1   = (unsigned short*)p; p += 512 * 512 * 2;
    unsigned short* Wt25  = (unsigned short*)p; p += 4 * 256 * 256 * 2;
    int* cnt    = (int*)p; p += (size_t)TGT * 4;
    int* off    = (int*)p; p += (size_t)TGT * 4;
    int* cursor = (int*)p; p += (size_t)TGT * 4;
    int* esrc   = (int*)p; p += (size_t)EDGES * 4;
    int* part   = (int*)p; p += 4096;

    const int SCAN_BLOCKS = (TGT + 511) / 512;        // 586

    // CSR build
    hipMemsetAsync(cnt, 0, (size_t)TGT * 4, stream);
    k_hist<<<EDGES / 256, 256, 0, stream>>>(target, cnt);
    k_scanb<<<SCAN_BLOCKS, 512, 0, stream>>>(cnt, off, part, TGT);
    k_scanp<<<1, 1024, 0, stream>>>(part, SCAN_BLOCKS);
    k_addoff<<<SCAN_BLOCKS, 512, 0, stream>>>(off, part, cursor, TGT);
    k_fill<<<EDGES / 256, 256, 0, stream>>>(target, src, cursor, esrc);

    // gather-aggregate + bf16 feats build (pre-swizzled)
    k_aggfeats<<<NN, 256, 0, stream>>>(x, off, cursor, esrc, (unsigned*)feats);

    // weight prep (Wt1 pre-swizzled; Wt25 tiled)
    k_wprep<<<2048, 256, 0, stream>>>(W_in, W_skip, W1_0, W2_0, W1_1, W2_1,
                                      Wt1, Wt25);

    const int GM = (NN + 127) / 128;                  // 782

    // GEMM1: h0 = silu(feats@W_in+b) swz bf16; gsk = feats@W_skip+b linear bf16
    k_gemm1<<<dim3(GM, 4), 256, 0, stream>>>(feats, Wt1, b_in, b_skip, h0, gsk);

    // fused residual block 0: h1 = silu(h0@W1_0+b1)@W2_0 + b2 + h0
    k_mlp<0><<<GM, 512, 0, stream>>>(h0, Wt25 + 0 * 65536, Wt25 + 1 * 65536,
                                     b1_0, b2_0, nullptr, h1, nullptr);
    // fused residual block 1 + gskip: out = silu(h1@W1_1+b1)@W2_1 + b2 + h1 + gsk
    k_mlp<1><<<GM, 512, 0, stream>>>(h1, Wt25 + 2 * 65536, Wt25 + 3 * 65536,
                                     b1_1, b2_1, gsk, nullptr, out);
}